// Round 1
// baseline (32089.014 us; speedup 1.0000x reference)
//
#include <hip/hip_runtime.h>

typedef unsigned short u16;
typedef unsigned int u32;

using bf16x8 = __attribute__((ext_vector_type(8))) __bf16;
using f32x4  = __attribute__((ext_vector_type(4))) float;

#define T_DIM 512
#define B_DIM 256
#define E_DIM 512
#define U_DIM 1024
#define K_DIM 1536   /* E+U */
#define NG    2048   /* 2U */

__device__ __forceinline__ u16 f2bf(float f) {
  union { float f; u32 u; } v; v.f = f;
  return (u16)((v.u + 0x7fffu + ((v.u >> 16) & 1u)) >> 16);
}

__global__ __launch_bounds__(256) void init_kernel(float* hF, u16* hB) {
  int i = blockIdx.x * 256 + threadIdx.x;
  hF[i] = 0.f;
  hB[i] = 0;
}

// W [K_DIM][N] fp32 -> Wt [N][K_DIM] bf16
__global__ __launch_bounds__(256) void wconv_kernel(const float* __restrict__ W,
                                                    u16* __restrict__ Wt, int N) {
  int k = blockIdx.x * 64 + (threadIdx.x & 63);
  int n = blockIdx.y * 4 + (threadIdx.x >> 6);
  Wt[(size_t)n * K_DIM + k] = f2bf(W[(size_t)k * N + n]);
}

// X[t*B+b][e] = bf16(embedder[inputs[t*B+b]][e])
__global__ __launch_bounds__(128) void embed_kernel(const int* __restrict__ inp,
                                                    const float* __restrict__ emb,
                                                    u16* __restrict__ X) {
  int rb = blockIdx.x;
  int idx = inp[rb];
  int e = threadIdx.x * 4;
  float4 v = *(const float4*)&emb[(size_t)idx * E_DIM + e];
  ushort4 o;
  o.x = f2bf(v.x); o.y = f2bf(v.y); o.z = f2bf(v.z); o.w = f2bf(v.w);
  *(ushort4*)&X[(size_t)rb * E_DIM + e] = o;
}

// One GRU half-step GEMM. A = [X_t (k<512) | Hb (k>=512)], B = Wt [N][1536].
// MODE 0 (gates, N=2048): pre->sigmoid; n<1024 -> rhb = bf16(r*h); n>=1024 -> zbuf = z
// MODE 1 (cand,  N=1024): pre->tanh; h' = z*h+(1-z)*c masked by t<len; write hF,hB
template <int MODE>
__global__ __launch_bounds__(256) void gru_gemm(
    const u16* __restrict__ X, const u16* __restrict__ Hb,
    const u16* __restrict__ Wt, const float* __restrict__ bias,
    float* __restrict__ hF, float* __restrict__ zbuf,
    u16* __restrict__ rhb, u16* __restrict__ hB,
    const int* __restrict__ lens, int t) {
  const int m0 = blockIdx.y * 64;
  const int n0 = blockIdx.x * 64;
  __shared__ __align__(16) u16 As[64 * 72];
  __shared__ __align__(16) u16 Bs[64 * 72];
  const int tid = threadIdx.x;
  const int lane = tid & 63, wave = tid >> 6;
  const int wm = wave >> 1, wn = wave & 1;
  const int l15 = lane & 15, kq = (lane >> 4) * 8;
  f32x4 acc00 = {0.f, 0.f, 0.f, 0.f}, acc01 = {0.f, 0.f, 0.f, 0.f};
  f32x4 acc10 = {0.f, 0.f, 0.f, 0.f}, acc11 = {0.f, 0.f, 0.f, 0.f};
  const u16* Xt = X + (size_t)t * (B_DIM * E_DIM);

  for (int kb = 0; kb < K_DIM; kb += 64) {
#pragma unroll
    for (int p = 0; p < 2; ++p) {
      int e = tid * 8 + p * 2048;
      int row = e >> 6, k = e & 63;
      const u16* asrc;
      if (kb < E_DIM) asrc = Xt + (size_t)(m0 + row) * E_DIM + kb + k;
      else            asrc = Hb + (size_t)(m0 + row) * U_DIM + (kb - E_DIM) + k;
      *(uint4*)&As[row * 72 + k] = *(const uint4*)asrc;
      const u16* bsrc = Wt + (size_t)(n0 + row) * K_DIM + kb + k;
      *(uint4*)&Bs[row * 72 + k] = *(const uint4*)bsrc;
    }
    __syncthreads();
#pragma unroll
    for (int kk = 0; kk < 64; kk += 32) {
      bf16x8 a0 = *(const bf16x8*)&As[(wm * 32 + l15) * 72 + kk + kq];
      bf16x8 a1 = *(const bf16x8*)&As[(wm * 32 + 16 + l15) * 72 + kk + kq];
      bf16x8 b0 = *(const bf16x8*)&Bs[(wn * 32 + l15) * 72 + kk + kq];
      bf16x8 b1 = *(const bf16x8*)&Bs[(wn * 32 + 16 + l15) * 72 + kk + kq];
      acc00 = __builtin_amdgcn_mfma_f32_16x16x32_bf16(a0, b0, acc00, 0, 0, 0);
      acc01 = __builtin_amdgcn_mfma_f32_16x16x32_bf16(a0, b1, acc01, 0, 0, 0);
      acc10 = __builtin_amdgcn_mfma_f32_16x16x32_bf16(a1, b0, acc10, 0, 0, 0);
      acc11 = __builtin_amdgcn_mfma_f32_16x16x32_bf16(a1, b1, acc11, 0, 0, 0);
    }
    __syncthreads();
  }

  const int lq = (lane >> 4) * 4;
#pragma unroll
  for (int i = 0; i < 2; ++i) {
#pragma unroll
    for (int j = 0; j < 2; ++j) {
      f32x4 acc = (i == 0) ? (j == 0 ? acc00 : acc01) : (j == 0 ? acc10 : acc11);
#pragma unroll
      for (int q = 0; q < 4; ++q) {
        int m = m0 + wm * 32 + i * 16 + lq + q;
        int n = n0 + wn * 32 + j * 16 + l15;
        float pre = acc[q] + bias[n];
        if (MODE == 0) {
          float g = 1.f / (1.f + __expf(-pre));
          if (n < U_DIM) {
            rhb[(size_t)m * U_DIM + n] = f2bf(g * hF[(size_t)m * U_DIM + n]);
          } else {
            zbuf[(size_t)m * U_DIM + (n - U_DIM)] = g;
          }
        } else {
          float c = tanhf(pre);
          size_t o = (size_t)m * U_DIM + n;
          float hold = hF[o];
          float z = zbuf[o];
          float hn = z * hold + (1.f - z) * c;
          float outv = (t < lens[m]) ? hn : hold;
          hF[o] = outv;
          hB[o] = f2bf(outv);
        }
      }
    }
  }
}

__global__ __launch_bounds__(256) void mlp1_kernel(const float* __restrict__ h,
                                                   const float* __restrict__ W1,
                                                   const float* __restrict__ b1,
                                                   float* __restrict__ o1) {
  int m = blockIdx.x, tid = threadIdx.x;
  __shared__ float xs[1024];
  for (int k = tid; k < 1024; k += 256) xs[k] = h[(size_t)m * 1024 + k];
  __syncthreads();
  for (int n = tid; n < 512; n += 256) {
    float s = b1[n];
    for (int k = 0; k < 1024; ++k) s += xs[k] * W1[(size_t)k * 512 + n];
    o1[(size_t)m * 512 + n] = fmaxf(s, 0.f);
  }
}

__global__ __launch_bounds__(256) void mlp2_kernel(const float* __restrict__ x,
                                                   const float* __restrict__ W2,
                                                   const float* __restrict__ b2,
                                                   float* __restrict__ o2) {
  int m = blockIdx.x, tid = threadIdx.x;
  __shared__ float xs[512];
  for (int k = tid; k < 512; k += 256) xs[k] = x[(size_t)m * 512 + k];
  __syncthreads();
  int n = tid;
  float s = b2[n];
  for (int k = 0; k < 512; ++k) s += xs[k] * W2[(size_t)k * 256 + n];
  o2[(size_t)m * 256 + n] = fmaxf(s, 0.f);
}

__global__ __launch_bounds__(256) void mlp3_kernel(const float* __restrict__ x,
                                                   const float* __restrict__ W3,
                                                   const float* __restrict__ b3,
                                                   float* __restrict__ out) {
  int m = blockIdx.x, tid = threadIdx.x;
  float xk = x[(size_t)m * 256 + tid];
  float p0 = xk * W3[tid * 2 + 0];
  float p1 = xk * W3[tid * 2 + 1];
#pragma unroll
  for (int off = 32; off; off >>= 1) {
    p0 += __shfl_down(p0, off);
    p1 += __shfl_down(p1, off);
  }
  __shared__ float s0[4], s1[4];
  int wave = tid >> 6, lane = tid & 63;
  if (lane == 0) { s0[wave] = p0; s1[wave] = p1; }
  __syncthreads();
  if (tid == 0) {
    float l0 = s0[0] + s0[1] + s0[2] + s0[3] + b3[0];
    float l1 = s1[0] + s1[1] + s1[2] + s1[3] + b3[1];
    out[m * 2 + 0] = l0;
    out[m * 2 + 1] = l1;
    float mx = fmaxf(l0, l1);
    float e0 = __expf(l0 - mx), e1 = __expf(l1 - mx);
    float inv = 1.f / (e0 + e1);
    out[512 + m * 2 + 0] = e0 * inv;
    out[512 + m * 2 + 1] = e1 * inv;
  }
}

extern "C" void kernel_launch(void* const* d_in, const int* in_sizes, int n_in,
                              void* d_out, int out_size, void* d_ws, size_t ws_size,
                              hipStream_t stream) {
  (void)in_sizes; (void)n_in; (void)out_size; (void)ws_size;
  const int* inputs = (const int*)d_in[0];
  const int* lens = (const int*)d_in[1];
  const float* embedder = (const float*)d_in[2];
  const float* Wg = (const float*)d_in[3];
  const float* bg = (const float*)d_in[4];
  const float* Wc = (const float*)d_in[5];
  const float* bc = (const float*)d_in[6];
  const float* W1 = (const float*)d_in[7];
  const float* b1 = (const float*)d_in[8];
  const float* W2 = (const float*)d_in[9];
  const float* b2 = (const float*)d_in[10];
  const float* W3 = (const float*)d_in[11];
  const float* b3 = (const float*)d_in[12];
  float* out = (float*)d_out;

  char* ws = (char*)d_ws;
  size_t off = 0;
  u16* X = (u16*)(ws + off);       off += (size_t)T_DIM * B_DIM * E_DIM * 2;   // 134.2 MB
  u16* WgT = (u16*)(ws + off);     off += (size_t)NG * K_DIM * 2;              // 6.3 MB
  u16* WcT = (u16*)(ws + off);     off += (size_t)U_DIM * K_DIM * 2;           // 3.1 MB
  float* hF = (float*)(ws + off);  off += (size_t)B_DIM * U_DIM * 4;
  u16* hB = (u16*)(ws + off);      off += (size_t)B_DIM * U_DIM * 2;
  u16* rhB = (u16*)(ws + off);     off += (size_t)B_DIM * U_DIM * 2;
  float* zb = (float*)(ws + off);  off += (size_t)B_DIM * U_DIM * 4;
  float* o1 = (float*)(ws + off);  off += (size_t)B_DIM * 512 * 4;
  float* o2 = (float*)(ws + off);  off += (size_t)B_DIM * 256 * 4;

  init_kernel<<<dim3(1024), dim3(256), 0, stream>>>(hF, hB);
  wconv_kernel<<<dim3(24, 512), dim3(256), 0, stream>>>(Wg, WgT, NG);
  wconv_kernel<<<dim3(24, 256), dim3(256), 0, stream>>>(Wc, WcT, U_DIM);
  embed_kernel<<<dim3(T_DIM * B_DIM), dim3(128), 0, stream>>>(inputs, embedder, X);

  for (int t = 0; t < T_DIM; ++t) {
    gru_gemm<0><<<dim3(32, 4), dim3(256), 0, stream>>>(X, hB, WgT, bg, hF, zb, rhB,
                                                       hB, lens, t);
    gru_gemm<1><<<dim3(16, 4), dim3(256), 0, stream>>>(X, rhB, WcT, bc, hF, zb, rhB,
                                                       hB, lens, t);
  }

  mlp1_kernel<<<dim3(256), dim3(256), 0, stream>>>(hF, W1, b1, o1);
  mlp2_kernel<<<dim3(256), dim3(256), 0, stream>>>(o1, W2, b2, o2);
  mlp3_kernel<<<dim3(256), dim3(256), 0, stream>>>(o2, W3, b3, out);
}